// Round 4
// baseline (20310.704 us; speedup 1.0000x reference)
//
#include <hip/hip_runtime.h>
#include <math.h>

// Backprop_29188597744223 — 1024-step sequential MLP training scan.
//
//   k_gram : G = X·Xᵀ (lower triangle + diag tiles), grid-parallel
//   k_z10  : Z10 = X·W1_init, grid-parallel
//   k2_seq : ONE workgroup, 1024 threads (16 waves). Thread (r,q) owns an
//            8x8 tile of W2 and 8x2 tile of W3 (80 persistent VGPRs ->
//            fits the 128-reg budget of a 1024-thr WG; no scratch spill).
//            W1 lazy (Gram trick; ||U1||² in double), W2/W3 renormalized
//            in place each step, z1p/o1 history share LDS buffer zo.
//   k_w1out: W1_final = s1_f·(W1_init + Xᵀ·diag(c)·O1), grid-parallel

#define LRC  0.01f
#define EPSV 1e-8f

// scl[] indices
#define S1  0
#define N2  1
#define N3  2
#define R2  3
#define R3  4
#define RB1 5
#define RB2 6
#define RB3 7

#define SMEM_FLOATS 36224
#define SMEM_BYTES  (SMEM_FLOATS * 4)

#define FMA16(c, a, b)                                                        \
  c[0][0] += a.x * b.x; c[0][1] += a.x * b.y; c[0][2] += a.x * b.z; c[0][3] += a.x * b.w; \
  c[1][0] += a.y * b.x; c[1][1] += a.y * b.y; c[1][2] += a.y * b.z; c[1][3] += a.y * b.w; \
  c[2][0] += a.z * b.x; c[2][1] += a.z * b.y; c[2][2] += a.z * b.z; c[2][3] += a.z * b.w; \
  c[3][0] += a.w * b.x; c[3][1] += a.w * b.y; c[3][2] += a.w * b.z; c[3][3] += a.w * b.w;

// ---------------------------------------------------------------- k_gram ----
__global__ __launch_bounds__(256) void k_gram(const float* __restrict__ X,
                                              float* __restrict__ G) {
  const int bi = blockIdx.y, bj = blockIdx.x;
  if (bj > bi) return;
  __shared__ float Xa[32][68];
  __shared__ float Xb[32][68];
  const int tid = threadIdx.x;
  const int tx = tid & 15, ty = tid >> 4;
  float c[4][4] = {};
  for (int k0 = 0; k0 < 1024; k0 += 32) {
    __syncthreads();
    {
      const int row = tid >> 2, kk = (tid & 3) * 8;
      const float* pa = X + (bi * 64 + row) * 1024 + k0 + kk;
      const float4 a0 = *(const float4*)pa;
      const float4 a1 = *(const float4*)(pa + 4);
      Xa[kk + 0][row] = a0.x; Xa[kk + 1][row] = a0.y;
      Xa[kk + 2][row] = a0.z; Xa[kk + 3][row] = a0.w;
      Xa[kk + 4][row] = a1.x; Xa[kk + 5][row] = a1.y;
      Xa[kk + 6][row] = a1.z; Xa[kk + 7][row] = a1.w;
      const float* pb = X + (bj * 64 + row) * 1024 + k0 + kk;
      const float4 b0 = *(const float4*)pb;
      const float4 b1 = *(const float4*)(pb + 4);
      Xb[kk + 0][row] = b0.x; Xb[kk + 1][row] = b0.y;
      Xb[kk + 2][row] = b0.z; Xb[kk + 3][row] = b0.w;
      Xb[kk + 4][row] = b1.x; Xb[kk + 5][row] = b1.y;
      Xb[kk + 6][row] = b1.z; Xb[kk + 7][row] = b1.w;
    }
    __syncthreads();
#pragma unroll
    for (int kk = 0; kk < 32; kk++) {
      const float4 a = *(const float4*)&Xa[kk][ty * 4];
      const float4 b = *(const float4*)&Xb[kk][tx * 4];
      FMA16(c, a, b)
    }
  }
#pragma unroll
  for (int ii = 0; ii < 4; ii++) {
    *(float4*)(G + (bi * 64 + ty * 4 + ii) * 1024 + bj * 64 + tx * 4) =
        make_float4(c[ii][0], c[ii][1], c[ii][2], c[ii][3]);
  }
}

// ----------------------------------------------------------------- k_z10 ----
__global__ __launch_bounds__(256) void k_z10(const float* __restrict__ X,
                                             const float* __restrict__ W1g,
                                             float* __restrict__ Z10) {
  const int bi = blockIdx.y, bj = blockIdx.x;
  __shared__ float At[32][68];
  __shared__ float Bt[32][68];
  const int tid = threadIdx.x;
  const int tx = tid & 15, ty = tid >> 4;
  float c[4][4] = {};
  for (int k0 = 0; k0 < 1024; k0 += 32) {
    __syncthreads();
    {
      const int row = tid >> 2, kk = (tid & 3) * 8;
      const float* pa = X + (bi * 64 + row) * 1024 + k0 + kk;
      const float4 a0 = *(const float4*)pa;
      const float4 a1 = *(const float4*)(pa + 4);
      At[kk + 0][row] = a0.x; At[kk + 1][row] = a0.y;
      At[kk + 2][row] = a0.z; At[kk + 3][row] = a0.w;
      At[kk + 4][row] = a1.x; At[kk + 5][row] = a1.y;
      At[kk + 6][row] = a1.z; At[kk + 7][row] = a1.w;
      const int kr = tid >> 3, j8 = (tid & 7) * 8;
      const float* pb = W1g + (k0 + kr) * 256 + bj * 64 + j8;
      *(float4*)&Bt[kr][j8]     = *(const float4*)pb;
      *(float4*)&Bt[kr][j8 + 4] = *(const float4*)(pb + 4);
    }
    __syncthreads();
#pragma unroll
    for (int kk = 0; kk < 32; kk++) {
      const float4 a = *(const float4*)&At[kk][ty * 4];
      const float4 b = *(const float4*)&Bt[kk][tx * 4];
      FMA16(c, a, b)
    }
  }
#pragma unroll
  for (int ii = 0; ii < 4; ii++) {
    *(float4*)(Z10 + (bi * 64 + ty * 4 + ii) * 256 + bj * 64 + tx * 4) =
        make_float4(c[ii][0], c[ii][1], c[ii][2], c[ii][3]);
  }
}

// --------------------------------------------------------------- k_w1out ----
__global__ __launch_bounds__(256) void k_w1out(
    const float* __restrict__ X, const float* __restrict__ o1g,
    const float* __restrict__ cg, const float* __restrict__ W1g,
    const float* __restrict__ sclg, float* __restrict__ outW1) {
  const int bi = blockIdx.y, bj = blockIdx.x;
  __shared__ float At[32][68];
  __shared__ float Bt[32][68];
  const int tid = threadIdx.x;
  const int tx = tid & 15, ty = tid >> 4;
  float c[4][4] = {};
  for (int k0 = 0; k0 < 1024; k0 += 32) {
    __syncthreads();
    {
      const int kr = tid >> 3, m8 = (tid & 7) * 8;
      const float* pa = X + (k0 + kr) * 1024 + bi * 64 + m8;
      *(float4*)&At[kr][m8]     = *(const float4*)pa;
      *(float4*)&At[kr][m8 + 4] = *(const float4*)(pa + 4);
      const float cs = cg[k0 + kr];
      const float* pb = o1g + (k0 + kr) * 256 + bj * 64 + m8;
      float4 b0 = *(const float4*)pb;
      float4 b1 = *(const float4*)(pb + 4);
      b0.x *= cs; b0.y *= cs; b0.z *= cs; b0.w *= cs;
      b1.x *= cs; b1.y *= cs; b1.z *= cs; b1.w *= cs;
      *(float4*)&Bt[kr][m8]     = b0;
      *(float4*)&Bt[kr][m8 + 4] = b1;
    }
    __syncthreads();
#pragma unroll
    for (int kk = 0; kk < 32; kk++) {
      const float4 a = *(const float4*)&At[kk][ty * 4];
      const float4 b = *(const float4*)&Bt[kk][tx * 4];
      FMA16(c, a, b)
    }
  }
  const float s1f = sclg[0];
#pragma unroll
  for (int ii = 0; ii < 4; ii++) {
    const int row = bi * 64 + ty * 4 + ii;
    const float4 w = *(const float4*)(W1g + row * 256 + bj * 64 + tx * 4);
    *(float4*)(outW1 + row * 256 + bj * 64 + tx * 4) =
        make_float4(s1f * (w.x + c[ii][0]), s1f * (w.y + c[ii][1]),
                    s1f * (w.z + c[ii][2]), s1f * (w.w + c[ii][3]));
  }
}

// ---------------------------------------------------------------- k2_seq ----
__device__ __forceinline__ float block_reduce16(float v, float* tmp, int tid) {
#pragma unroll
  for (int off = 32; off > 0; off >>= 1) v += __shfl_xor(v, off);
  __syncthreads();
  if ((tid & 63) == 0) tmp[tid >> 6] = v;
  __syncthreads();
  float s = 0.f;
#pragma unroll
  for (int w = 0; w < 16; w++) s += tmp[w];
  return s;
}

__global__ __launch_bounds__(1024) void k2_seq(
    const float* __restrict__ Tg, const float* __restrict__ W1g,
    const float* __restrict__ b1g, const float* __restrict__ W2g,
    const float* __restrict__ b2g, const float* __restrict__ W3g,
    const float* __restrict__ b3g, const float* __restrict__ G,
    const float* __restrict__ Z10, float* __restrict__ o1g,
    float* __restrict__ cg, float* __restrict__ sclg,
    float* __restrict__ outW2, float* __restrict__ outW3) {
  extern __shared__ float sm[];
  __shared__ double n1d;           // ||U1||^2 tracked in double (tid0 only)
  float* const zo  = sm;           // [64][260]: z1p row l until step l, then o1
  float* const Gb  = sm + 16640;   // [64][64] plain / [64][33] prefix staging
  float* const scr = sm + 20736;   // 8448 floats: partials / o1 staging
  float* const Tb  = sm + 29184;   // [64][64] targets for this block
  float* const a1v = sm + 33280;
  float* const z1v = sm + 33536;
  float* const z2v = sm + 33792;
  float* const a2v = sm + 34048;
  float* const o2v = sm + 34304;
  float* const o1v = sm + 34560;
  float* const b1v = sm + 34816;
  float* const b2v = sm + 35072;
  float* const b1p = sm + 35328;
  float* const b2p = sm + 35584;
  float* const z3v = sm + 35840;   // 64
  float* const d3v = sm + 35904;   // 64
  float* const b3v = sm + 35968;   // 64
  float* const b3p = sm + 36032;   // 64
  float* const ch  = sm + 36096;   // 64
  float* const dts = sm + 36160;   // 16
  float* const scl = sm + 36176;   // 16
  float* const cpre = sm + 36192;  // 32

  const int tid = threadIdx.x;
  const int r = tid >> 5;  // 0..31 : 8-row group
  const int q = tid & 31;  // 0..31 : 8-col group (W2) / 2-col group (W3)

  // Register-resident W2/W3 tiles — ALWAYS the true (normalized) weights.
  float U2[8][8];
  float U3[8][2];
#pragma unroll
  for (int i = 0; i < 8; i++) {
    const int row = r * 8 + i;
    const float4 v0 = *(const float4*)(W2g + row * 256 + q * 8);
    const float4 v1 = *(const float4*)(W2g + row * 256 + q * 8 + 4);
    U2[i][0] = v0.x; U2[i][1] = v0.y; U2[i][2] = v0.z; U2[i][3] = v0.w;
    U2[i][4] = v1.x; U2[i][5] = v1.y; U2[i][6] = v1.z; U2[i][7] = v1.w;
    const float2 w3v = *(const float2*)(W3g + row * 64 + q * 2);
    U3[i][0] = w3v.x; U3[i][1] = w3v.y;
  }
  if (tid < 256) { b1v[tid] = b1g[tid]; b2v[tid] = b2g[tid]; }
  if (tid < 64) b3v[tid] = b3g[tid];

  // Initial squared norms.
  float acc1 = 0.f;
  for (int i = tid; i < 65536; i += 1024) {
    const float4 v = ((const float4*)W1g)[i];
    acc1 += v.x * v.x + v.y * v.y + v.z * v.z + v.w * v.w;
  }
  const float n1init = block_reduce16(acc1, scr, tid);
  float acc2 = 0.f;
#pragma unroll
  for (int i = 0; i < 8; i++)
#pragma unroll
    for (int j = 0; j < 8; j++) acc2 += U2[i][j] * U2[i][j];
  const float n2init = block_reduce16(acc2, scr, tid);
  float acc3 = 0.f;
#pragma unroll
  for (int i = 0; i < 8; i++)
    acc3 += U3[i][0] * U3[i][0] + U3[i][1] * U3[i][1];
  const float n3init = block_reduce16(acc3, scr, tid);
  if (tid == 0) {
    scl[S1] = 1.f;
    scl[N2] = n2init; scl[N3] = n3init;
    n1d = (double)n1init;
  }
  __syncthreads();

  for (int b = 0; b < 16; b++) {
    const int bs = b * 64;
    // ---- prefix: zo[row][j] = Z10[bs+row][j] + sum_{s<bs} cg[s]G[bs+row][s]o1[s][j]
    {
      float pacc[2][8];
#pragma unroll
      for (int rr = 0; rr < 2; rr++)
#pragma unroll
        for (int jj = 0; jj < 8; jj++) pacc[rr][jj] = 0.f;
      for (int c0 = 0; c0 < bs; c0 += 32) {
        __syncthreads();
        if (tid < 32) cpre[tid] = cg[c0 + tid];
        if (tid < 512) {
          const int row = tid >> 3, k4 = (tid & 7) * 4;
          const float4 gv = *(const float4*)(G + (bs + row) * 1024 + c0 + k4);
          Gb[row * 33 + k4 + 0] = gv.x; Gb[row * 33 + k4 + 1] = gv.y;
          Gb[row * 33 + k4 + 2] = gv.z; Gb[row * 33 + k4 + 3] = gv.w;
        }
        ((float4*)scr)[tid]        = ((const float4*)(o1g + c0 * 256))[tid];
        ((float4*)scr)[tid + 1024] = ((const float4*)(o1g + c0 * 256))[tid + 1024];
        __syncthreads();
#pragma unroll 2
        for (int ss = 0; ss < 32; ss++) {
          const float cs = cpre[ss];
          const float4 oA = *(const float4*)(scr + ss * 256 + q * 8);
          const float4 oB = *(const float4*)(scr + ss * 256 + q * 8 + 4);
#pragma unroll
          for (int rr = 0; rr < 2; rr++) {
            const float g = Gb[(r * 2 + rr) * 33 + ss] * cs;
            pacc[rr][0] += g * oA.x; pacc[rr][1] += g * oA.y;
            pacc[rr][2] += g * oA.z; pacc[rr][3] += g * oA.w;
            pacc[rr][4] += g * oB.x; pacc[rr][5] += g * oB.y;
            pacc[rr][6] += g * oB.z; pacc[rr][7] += g * oB.w;
          }
        }
      }
      __syncthreads();
#pragma unroll
      for (int rr = 0; rr < 2; rr++) {
        const int row = r * 2 + rr;
        float4 z0 = *(const float4*)(Z10 + (bs + row) * 256 + q * 8);
        float4 z1 = *(const float4*)(Z10 + (bs + row) * 256 + q * 8 + 4);
        z0.x += pacc[rr][0]; z0.y += pacc[rr][1];
        z0.z += pacc[rr][2]; z0.w += pacc[rr][3];
        z1.x += pacc[rr][4]; z1.y += pacc[rr][5];
        z1.z += pacc[rr][6]; z1.w += pacc[rr][7];
        *(float4*)(zo + row * 260 + q * 8) = z0;
        *(float4*)(zo + row * 260 + q * 8 + 4) = z1;
      }
      // this block's 64x64 Gram square (plain layout) + targets
      {
        const int row = tid >> 4, c4 = tid & 15;
        *(float4*)(Gb + row * 64 + c4 * 4) =
            *(const float4*)(G + (bs + row) * 1024 + bs + c4 * 4);
      }
      ((float4*)Tb)[tid] = ((const float4*)(Tg + bs * 64))[tid];
      __syncthreads();
    }

    // ---- 64 sequential steps
    for (int l = 0; l < 64; l++) {
      const int t = bs + l;
      // A: z1u = zo[l] (z1p) + in-block history; a1 = sigmoid(s1*z1u + b1)
      {
        const int j = tid >> 2, half = tid & 3;
        float a = 0.f;
        for (int lp = half; lp < l; lp += 4)
          a += ch[lp] * Gb[l * 64 + lp] * zo[lp * 260 + j];
        a += __shfl_xor(a, 1);
        a += __shfl_xor(a, 2);
        if (half == 0) {
          const float z1u = zo[l * 260 + j] + a;
          z1v[j] = z1u;
          const float z = scl[S1] * z1u + b1v[j];
          a1v[j] = 1.f / (1.f + expf(-z));
        }
      }
      __syncthreads();
      // B1: z2 partials = a1 @ U2
      {
        float av[8];
#pragma unroll
        for (int i = 0; i < 8; i++) av[i] = a1v[r * 8 + i];
        float acc[8];
#pragma unroll
        for (int j = 0; j < 8; j++) acc[j] = 0.f;
#pragma unroll
        for (int i = 0; i < 8; i++)
#pragma unroll
          for (int j = 0; j < 8; j++) acc[j] += av[i] * U2[i][j];
        *(float4*)&scr[r * 264 + q * 8] =
            make_float4(acc[0], acc[1], acc[2], acc[3]);
        *(float4*)&scr[r * 264 + q * 8 + 4] =
            make_float4(acc[4], acc[5], acc[6], acc[7]);
      }
      __syncthreads();
      // B2
      if (tid < 256) {
        float s = 0.f;
#pragma unroll
        for (int rr = 0; rr < 32; rr++) s += scr[rr * 264 + tid];
        z2v[tid] = s;
        a2v[tid] = 1.f / (1.f + expf(-(s + b2v[tid])));
      }
      __syncthreads();
      // C1: z3 partials = a2 @ U3
      {
        float c0a = 0.f, c1a = 0.f;
#pragma unroll
        for (int i = 0; i < 8; i++) {
          const float a2x = a2v[r * 8 + i];
          c0a += a2x * U3[i][0];
          c1a += a2x * U3[i][1];
        }
        scr[(q * 2 + 0) * 33 + r] = c0a;
        scr[(q * 2 + 1) * 33 + r] = c1a;
      }
      __syncthreads();
      // C2: z3, a3, softmax(-a3), d3, b3'
      if (tid < 64) {
        float s = 0.f;
#pragma unroll
        for (int rr = 0; rr < 32; rr++) s += scr[tid * 33 + rr];
        z3v[tid] = s;
        const float a3 = 1.f / (1.f + expf(-(s + b3v[tid])));
        const float e = expf(-a3);
        float tot = e;
#pragma unroll
        for (int off = 32; off > 0; off >>= 1) tot += __shfl_xor(tot, off);
        const float outv = e / tot;
        const float d3 = (Tb[l * 64 + tid] - outv) * a3 * (1.f - a3);
        d3v[tid] = d3;
        b3p[tid] = b3v[tid] - LRC * d3;
      }
      __syncthreads();
      // E1: o2 partials = U3 @ d3
      {
        const float d0 = d3v[q * 2 + 0], d1 = d3v[q * 2 + 1];
#pragma unroll
        for (int i = 0; i < 8; i++)
          scr[(r * 8 + i) * 33 + q] = U3[i][0] * d0 + U3[i][1] * d1;
      }
      __syncthreads();
      // E2
      if (tid < 256) {
        float s = 0.f;
#pragma unroll
        for (int qq = 0; qq < 32; qq++) s += scr[tid * 33 + qq];
        const float a2x = a2v[tid];
        const float o2 = s * a2x * (1.f - a2x);
        o2v[tid] = o2;
        b2p[tid] = b2v[tid] - LRC * o2;
      }
      __syncthreads();
      // F1: o1 partials = U2 @ o2
      {
        float ov[8];
#pragma unroll
        for (int j = 0; j < 8; j++) ov[j] = o2v[q * 8 + j];
#pragma unroll
        for (int i = 0; i < 8; i++) {
          float s = 0.f;
#pragma unroll
          for (int j = 0; j < 8; j++) s += U2[i][j] * ov[j];
          scr[(r * 8 + i) * 33 + q] = s;
        }
      }
      __syncthreads();
      // F2
      if (tid < 256) {
        float s = 0.f;
#pragma unroll
        for (int qq = 0; qq < 32; qq++) s += scr[tid * 33 + qq];
        const float a1x = a1v[tid];
        const float o1x = s * a1x * (1.f - a1x);
        o1v[tid] = o1x;
        zo[l * 260 + tid] = o1x;          // overwrite z1p row l with o1
        o1g[t * 256 + tid] = o1x;
        b1p[tid] = b1v[tid] - LRC * o1x;
      }
      __syncthreads();
      // G: batched dots — one per wave (16 waves, 11 dots)
      {
        const int w = tid >> 6, lane = tid & 63;
        float v = 0.f;
        if (w == 0)      { for (int i = lane; i < 256; i += 64) v += z1v[i] * o1v[i]; }
        else if (w == 1) { for (int i = lane; i < 256; i += 64) v += o1v[i] * o1v[i]; }
        else if (w == 2) { for (int i = lane; i < 256; i += 64) v += z2v[i] * o2v[i]; }
        else if (w == 3) { for (int i = lane; i < 256; i += 64) v += a1v[i] * a1v[i]; }
        else if (w == 4) { for (int i = lane; i < 256; i += 64) v += o2v[i] * o2v[i]; }
        else if (w == 5) { v = z3v[lane] * d3v[lane]; }
        else if (w == 6) { for (int i = lane; i < 256; i += 64) v += a2v[i] * a2v[i]; }
        else if (w == 7) { v = d3v[lane] * d3v[lane]; }
        else if (w == 8) { for (int i = lane; i < 256; i += 64) v += b1p[i] * b1p[i]; }
        else if (w == 9) { for (int i = lane; i < 256; i += 64) v += b2p[i] * b2p[i]; }
        else if (w == 10){ v = b3p[lane] * b3p[lane]; }
#pragma unroll
        for (int off = 32; off > 0; off >>= 1) v += __shfl_xor(v, off);
        if (lane == 0 && w < 11) dts[w] = v;
      }
      __syncthreads();
      // scalar recurrences
      if (tid == 0) {
        const float s1 = scl[S1];
        const float c1 = -LRC / s1;
        const double gtt = (double)Gb[l * 64 + l];
        const double n1 = n1d + 2.0 * (double)c1 * (double)dts[0] +
                          (double)c1 * (double)c1 * gtt * (double)dts[1];
        n1d = n1;
        const double w1n = (double)s1 * sqrt(n1);
        scl[S1] = (float)((double)s1 / fmax(w1n, (double)EPSV));
        ch[l] = c1;
        cg[t] = c1;
        const float n2p =
            scl[N2] - 2.f * LRC * dts[2] + LRC * LRC * dts[3] * dts[4];
        const float r2 = 1.f / fmaxf(sqrtf(n2p), EPSV);
        scl[R2] = r2;
        scl[N2] = n2p * r2 * r2;
        const float n3p =
            scl[N3] - 2.f * LRC * dts[5] + LRC * LRC * dts[6] * dts[7];
        const float r3 = 1.f / fmaxf(sqrtf(n3p), EPSV);
        scl[R3] = r3;
        scl[N3] = n3p * r3 * r3;
        scl[RB1] = 1.f / fmaxf(sqrtf(dts[8]), EPSV);
        scl[RB2] = 1.f / fmaxf(sqrtf(dts[9]), EPSV);
        scl[RB3] = 1.f / fmaxf(sqrtf(dts[10]), EPSV);
      }
      __syncthreads();
      // H: rank-1 update + renormalize W2/W3 in registers; bias renorm
      {
        const float r2s = scl[R2], r3s = scl[R3];
        float ov[8];
#pragma unroll
        for (int j = 0; j < 8; j++) ov[j] = -LRC * r2s * o2v[q * 8 + j];
        const float d0 = -LRC * r3s * d3v[q * 2 + 0];
        const float d1 = -LRC * r3s * d3v[q * 2 + 1];
#pragma unroll
        for (int i = 0; i < 8; i++) {
          const float a1x = a1v[r * 8 + i];
#pragma unroll
          for (int j = 0; j < 8; j++)
            U2[i][j] = U2[i][j] * r2s + a1x * ov[j];
          const float a2x = a2v[r * 8 + i];
          U3[i][0] = U3[i][0] * r3s + a2x * d0;
          U3[i][1] = U3[i][1] * r3s + a2x * d1;
        }
        if (tid < 256) {
          b1v[tid] = b1p[tid] * scl[RB1];
          b2v[tid] = b2p[tid] * scl[RB2];
        }
        if (tid < 64) b3v[tid] = b3p[tid] * scl[RB3];
      }
      __syncthreads();
    }
  }

  if (tid == 0) sclg[0] = scl[S1];
#pragma unroll
  for (int i = 0; i < 8; i++) {
    const int row = r * 8 + i;
    *(float4*)(outW2 + row * 256 + q * 8) =
        make_float4(U2[i][0], U2[i][1], U2[i][2], U2[i][3]);
    *(float4*)(outW2 + row * 256 + q * 8 + 4) =
        make_float4(U2[i][4], U2[i][5], U2[i][6], U2[i][7]);
    *(float2*)(outW3 + row * 64 + q * 2) = make_float2(U3[i][0], U3[i][1]);
  }
}

// ---------------------------------------------------------------- launch ----
extern "C" void kernel_launch(void* const* d_in, const int* in_sizes, int n_in,
                              void* d_out, int out_size, void* d_ws,
                              size_t ws_size, hipStream_t stream) {
  (void)in_sizes; (void)n_in; (void)out_size; (void)ws_size;
  const float* X   = (const float*)d_in[0];
  const float* Tg  = (const float*)d_in[1];
  const float* W1g = (const float*)d_in[2];
  const float* b1g = (const float*)d_in[3];
  const float* W2g = (const float*)d_in[4];
  const float* b2g = (const float*)d_in[5];
  const float* W3g = (const float*)d_in[6];
  const float* b3g = (const float*)d_in[7];
  float* out = (float*)d_out;
  float* ws  = (float*)d_ws;

  float* G    = ws;
  float* Z10  = G + 1048576;
  float* o1g  = Z10 + 262144;
  float* cg   = o1g + 262144;
  float* sclg = cg + 1024;

  (void)hipFuncSetAttribute((const void*)k2_seq,
                            hipFuncAttributeMaxDynamicSharedMemorySize,
                            SMEM_BYTES);

  k_gram<<<dim3(16, 16), 256, 0, stream>>>(X, G);
  k_z10<<<dim3(4, 16), 256, 0, stream>>>(X, W1g, Z10);
  k2_seq<<<dim3(1), dim3(1024), SMEM_BYTES, stream>>>(
      Tg, W1g, b1g, W2g, b2g, W3g, b3g, G, Z10, o1g, cg, sclg,
      out + 262144, out + 327680);
  k_w1out<<<dim3(4, 16), 256, 0, stream>>>(X, o1g, cg, W1g, sclg, out);
}

// Round 5
// 16121.535 us; speedup vs baseline: 1.2598x; 1.2598x over previous
//
#include <hip/hip_runtime.h>
#include <math.h>

// Backprop_29188597744223 — 1024-step sequential MLP training scan.
//
//   k_gram : G = X·Xᵀ (lower triangle + diag tiles), grid-parallel
//   k_z10  : Z10 = X·W1_init, grid-parallel
//   k2_seq : ONE workgroup, 1024 threads (16 waves). Thread (r,q) owns an
//            8x8 tile of W2 (8 named ext_vector f32x8 SSA values — cannot
//            become an alloca/scratch) and an 8x2 tile of W3 (16 scalars).
//            W1 lazy (Gram trick; ||U1||² recurrence replicated per-thread
//            in double), W2/W3 renormalized in place each step.
//   k_w1out: W1_final = s1_f·(W1_init + Xᵀ·diag(c)·O1), grid-parallel

#define LRC  0.01f
#define EPSV 1e-8f

typedef float f32x8 __attribute__((ext_vector_type(8)));

#define SMEM_FLOATS 36976
#define SMEM_BYTES  (SMEM_FLOATS * 4)

#define ROWS8(OP) OP(0) OP(1) OP(2) OP(3) OP(4) OP(5) OP(6) OP(7)

__device__ __forceinline__ float hsum8(f32x8 v) {
  return ((v.s0 + v.s1) + (v.s2 + v.s3)) + ((v.s4 + v.s5) + (v.s6 + v.s7));
}

#define FMA16(c, a, b)                                                        \
  c[0][0] += a.x * b.x; c[0][1] += a.x * b.y; c[0][2] += a.x * b.z; c[0][3] += a.x * b.w; \
  c[1][0] += a.y * b.x; c[1][1] += a.y * b.y; c[1][2] += a.y * b.z; c[1][3] += a.y * b.w; \
  c[2][0] += a.z * b.x; c[2][1] += a.z * b.y; c[2][2] += a.z * b.z; c[2][3] += a.z * b.w; \
  c[3][0] += a.w * b.x; c[3][1] += a.w * b.y; c[3][2] += a.w * b.z; c[3][3] += a.w * b.w;

// ---------------------------------------------------------------- k_gram ----
__global__ __launch_bounds__(256) void k_gram(const float* __restrict__ X,
                                              float* __restrict__ G) {
  const int bi = blockIdx.y, bj = blockIdx.x;
  if (bj > bi) return;
  __shared__ float Xa[32][68];
  __shared__ float Xb[32][68];
  const int tid = threadIdx.x;
  const int tx = tid & 15, ty = tid >> 4;
  float c[4][4] = {};
  for (int k0 = 0; k0 < 1024; k0 += 32) {
    __syncthreads();
    {
      const int row = tid >> 2, kk = (tid & 3) * 8;
      const float* pa = X + (bi * 64 + row) * 1024 + k0 + kk;
      const float4 a0 = *(const float4*)pa;
      const float4 a1 = *(const float4*)(pa + 4);
      Xa[kk + 0][row] = a0.x; Xa[kk + 1][row] = a0.y;
      Xa[kk + 2][row] = a0.z; Xa[kk + 3][row] = a0.w;
      Xa[kk + 4][row] = a1.x; Xa[kk + 5][row] = a1.y;
      Xa[kk + 6][row] = a1.z; Xa[kk + 7][row] = a1.w;
      const float* pb = X + (bj * 64 + row) * 1024 + k0 + kk;
      const float4 b0 = *(const float4*)pb;
      const float4 b1 = *(const float4*)(pb + 4);
      Xb[kk + 0][row] = b0.x; Xb[kk + 1][row] = b0.y;
      Xb[kk + 2][row] = b0.z; Xb[kk + 3][row] = b0.w;
      Xb[kk + 4][row] = b1.x; Xb[kk + 5][row] = b1.y;
      Xb[kk + 6][row] = b1.z; Xb[kk + 7][row] = b1.w;
    }
    __syncthreads();
#pragma unroll
    for (int kk = 0; kk < 32; kk++) {
      const float4 a = *(const float4*)&Xa[kk][ty * 4];
      const float4 b = *(const float4*)&Xb[kk][tx * 4];
      FMA16(c, a, b)
    }
  }
#pragma unroll
  for (int ii = 0; ii < 4; ii++) {
    *(float4*)(G + (bi * 64 + ty * 4 + ii) * 1024 + bj * 64 + tx * 4) =
        make_float4(c[ii][0], c[ii][1], c[ii][2], c[ii][3]);
  }
}

// ----------------------------------------------------------------- k_z10 ----
__global__ __launch_bounds__(256) void k_z10(const float* __restrict__ X,
                                             const float* __restrict__ W1g,
                                             float* __restrict__ Z10) {
  const int bi = blockIdx.y, bj = blockIdx.x;
  __shared__ float At[32][68];
  __shared__ float Bt[32][68];
  const int tid = threadIdx.x;
  const int tx = tid & 15, ty = tid >> 4;
  float c[4][4] = {};
  for (int k0 = 0; k0 < 1024; k0 += 32) {
    __syncthreads();
    {
      const int row = tid >> 2, kk = (tid & 3) * 8;
      const float* pa = X + (bi * 64 + row) * 1024 + k0 + kk;
      const float4 a0 = *(const float4*)pa;
      const float4 a1 = *(const float4*)(pa + 4);
      At[kk + 0][row] = a0.x; At[kk + 1][row] = a0.y;
      At[kk + 2][row] = a0.z; At[kk + 3][row] = a0.w;
      At[kk + 4][row] = a1.x; At[kk + 5][row] = a1.y;
      At[kk + 6][row] = a1.z; At[kk + 7][row] = a1.w;
      const int kr = tid >> 3, j8 = (tid & 7) * 8;
      const float* pb = W1g + (k0 + kr) * 256 + bj * 64 + j8;
      *(float4*)&Bt[kr][j8]     = *(const float4*)pb;
      *(float4*)&Bt[kr][j8 + 4] = *(const float4*)(pb + 4);
    }
    __syncthreads();
#pragma unroll
    for (int kk = 0; kk < 32; kk++) {
      const float4 a = *(const float4*)&At[kk][ty * 4];
      const float4 b = *(const float4*)&Bt[kk][tx * 4];
      FMA16(c, a, b)
    }
  }
#pragma unroll
  for (int ii = 0; ii < 4; ii++) {
    *(float4*)(Z10 + (bi * 64 + ty * 4 + ii) * 256 + bj * 64 + tx * 4) =
        make_float4(c[ii][0], c[ii][1], c[ii][2], c[ii][3]);
  }
}

// --------------------------------------------------------------- k_w1out ----
__global__ __launch_bounds__(256) void k_w1out(
    const float* __restrict__ X, const float* __restrict__ o1g,
    const float* __restrict__ cg, const float* __restrict__ W1g,
    const float* __restrict__ sclg, float* __restrict__ outW1) {
  const int bi = blockIdx.y, bj = blockIdx.x;
  __shared__ float At[32][68];
  __shared__ float Bt[32][68];
  const int tid = threadIdx.x;
  const int tx = tid & 15, ty = tid >> 4;
  float c[4][4] = {};
  for (int k0 = 0; k0 < 1024; k0 += 32) {
    __syncthreads();
    {
      const int kr = tid >> 3, m8 = (tid & 7) * 8;
      const float* pa = X + (k0 + kr) * 1024 + bi * 64 + m8;
      *(float4*)&At[kr][m8]     = *(const float4*)pa;
      *(float4*)&At[kr][m8 + 4] = *(const float4*)(pa + 4);
      const float cs = cg[k0 + kr];
      const float* pb = o1g + (k0 + kr) * 256 + bj * 64 + m8;
      float4 b0 = *(const float4*)pb;
      float4 b1 = *(const float4*)(pb + 4);
      b0.x *= cs; b0.y *= cs; b0.z *= cs; b0.w *= cs;
      b1.x *= cs; b1.y *= cs; b1.z *= cs; b1.w *= cs;
      *(float4*)&Bt[kr][m8]     = b0;
      *(float4*)&Bt[kr][m8 + 4] = b1;
    }
    __syncthreads();
#pragma unroll
    for (int kk = 0; kk < 32; kk++) {
      const float4 a = *(const float4*)&At[kk][ty * 4];
      const float4 b = *(const float4*)&Bt[kk][tx * 4];
      FMA16(c, a, b)
    }
  }
  const float s1f = sclg[0];
#pragma unroll
  for (int ii = 0; ii < 4; ii++) {
    const int row = bi * 64 + ty * 4 + ii;
    const float4 w = *(const float4*)(W1g + row * 256 + bj * 64 + tx * 4);
    *(float4*)(outW1 + row * 256 + bj * 64 + tx * 4) =
        make_float4(s1f * (w.x + c[ii][0]), s1f * (w.y + c[ii][1]),
                    s1f * (w.z + c[ii][2]), s1f * (w.w + c[ii][3]));
  }
}

// ---------------------------------------------------------------- k2_seq ----
__device__ __forceinline__ float block_reduce16(float v, float* tmp, int tid) {
#pragma unroll
  for (int off = 32; off > 0; off >>= 1) v += __shfl_xor(v, off);
  __syncthreads();
  if ((tid & 63) == 0) tmp[tid >> 6] = v;
  __syncthreads();
  float s = 0.f;
#pragma unroll
  for (int w = 0; w < 16; w++) s += tmp[w];
  __syncthreads();
  return s;
}

__global__ __attribute__((amdgpu_flat_work_group_size(1024, 1024)))
__attribute__((amdgpu_waves_per_eu(4, 4))) void k2_seq(
    const float* __restrict__ Tg, const float* __restrict__ W1g,
    const float* __restrict__ b1g, const float* __restrict__ W2g,
    const float* __restrict__ b2g, const float* __restrict__ W3g,
    const float* __restrict__ b3g, const float* __restrict__ G,
    const float* __restrict__ Z10, float* __restrict__ o1g,
    float* __restrict__ cg, float* __restrict__ sclg,
    float* __restrict__ outW2, float* __restrict__ outW3) {
  extern __shared__ float sm[];
  float* const zo  = sm;           // [64][272]: z1p row l until step l, then o1
  float* const Gb  = sm + 17408;   // [64][64] plain / [64][33] prefix staging
  float* const scr = sm + 21504;   // 8448 floats: partials / o1 staging
  float* const Tb  = sm + 29952;   // [64][64] targets for this block
  float* const a1v = sm + 34048;
  float* const z1v = sm + 34304;
  float* const z2v = sm + 34560;
  float* const a2v = sm + 34816;
  float* const o2v = sm + 35072;
  float* const o1v = sm + 35328;
  float* const b1v = sm + 35584;
  float* const b2v = sm + 35840;
  float* const b1p = sm + 36096;
  float* const b2p = sm + 36352;
  float* const z3v = sm + 36608;   // 64
  float* const d3v = sm + 36672;   // 64
  float* const b3v = sm + 36736;   // 64
  float* const b3p = sm + 36800;   // 64
  float* const ch  = sm + 36864;   // 64
  float* const dts = sm + 36928;   // 16
  float* const cpre = sm + 36944;  // 32

  const int tid = threadIdx.x;
  const int r = tid >> 5;  // 0..31 : 8-row group
  const int q = tid & 31;  // 0..31 : 8-col group (W2) / 2-col group (W3)

  // ---- persistent per-thread state as SSA values (no arrays!) ----
  f32x8 W2_0, W2_1, W2_2, W2_3, W2_4, W2_5, W2_6, W2_7;
  float W3x_0, W3x_1, W3x_2, W3x_3, W3x_4, W3x_5, W3x_6, W3x_7;
  float W3y_0, W3y_1, W3y_2, W3y_3, W3y_4, W3y_5, W3y_6, W3y_7;

#define INIT_ROW(i)                                                           \
  { const int row = r * 8 + i;                                                \
    W2_##i  = *(const f32x8*)(W2g + row * 256 + q * 8);                       \
    W3x_##i = W3g[row * 64 + q * 2];                                          \
    W3y_##i = W3g[row * 64 + q * 2 + 1]; }
  ROWS8(INIT_ROW)

  if (tid < 256) { b1v[tid] = b1g[tid]; b2v[tid] = b2g[tid]; }
  if (tid < 64) b3v[tid] = b3g[tid];

  // Initial squared norms (results broadcast to all threads).
  float acc1 = 0.f;
  for (int i = tid; i < 65536; i += 1024) {
    const float4 v = ((const float4*)W1g)[i];
    acc1 += v.x * v.x + v.y * v.y + v.z * v.z + v.w * v.w;
  }
  const float n1init = block_reduce16(acc1, scr, tid);
  float acc2 = 0.f;
#define N2_ROW(i) { f32x8 t = W2_##i * W2_##i; acc2 += hsum8(t); }
  ROWS8(N2_ROW)
  const float n2init = block_reduce16(acc2, scr, tid);
  float acc3 = 0.f;
#define N3_ROW(i) acc3 += W3x_##i * W3x_##i + W3y_##i * W3y_##i;
  ROWS8(N3_ROW)
  const float n3init = block_reduce16(acc3, scr, tid);

  // Per-thread replicated recurrence state (identical on all threads).
  float s1 = 1.f;
  double n1d = (double)n1init;
  float n2 = n2init, n3 = n3init;
  __syncthreads();

  for (int b = 0; b < 16; b++) {
    const int bs = b * 64;
    // ---- prefix: zo[row][j] = Z10[bs+row][j] + sum_{s<bs} cg[s]G[bs+row][s]o1[s][j]
    {
      f32x8 pacc0 = {0.f, 0.f, 0.f, 0.f, 0.f, 0.f, 0.f, 0.f};
      f32x8 pacc1 = {0.f, 0.f, 0.f, 0.f, 0.f, 0.f, 0.f, 0.f};
      for (int c0 = 0; c0 < bs; c0 += 32) {
        __syncthreads();
        if (tid < 32) cpre[tid] = cg[c0 + tid];
        if (tid < 512) {
          const int row = tid >> 3, k4 = (tid & 7) * 4;
          const float4 gv = *(const float4*)(G + (bs + row) * 1024 + c0 + k4);
          Gb[row * 33 + k4 + 0] = gv.x; Gb[row * 33 + k4 + 1] = gv.y;
          Gb[row * 33 + k4 + 2] = gv.z; Gb[row * 33 + k4 + 3] = gv.w;
        }
        ((float4*)scr)[tid]        = ((const float4*)(o1g + c0 * 256))[tid];
        ((float4*)scr)[tid + 1024] = ((const float4*)(o1g + c0 * 256))[tid + 1024];
        __syncthreads();
#pragma unroll 2
        for (int ss = 0; ss < 32; ss++) {
          const float cs = cpre[ss];
          const f32x8 o8 = *(const f32x8*)(scr + ss * 256 + q * 8);
          const float g0 = Gb[(r * 2 + 0) * 33 + ss] * cs;
          const float g1 = Gb[(r * 2 + 1) * 33 + ss] * cs;
          pacc0 += g0 * o8;
          pacc1 += g1 * o8;
        }
      }
      __syncthreads();
      {
        const int row0 = r * 2;
        const f32x8 z0 = *(const f32x8*)(Z10 + (bs + row0) * 256 + q * 8) + pacc0;
        const f32x8 z1 = *(const f32x8*)(Z10 + (bs + row0 + 1) * 256 + q * 8) + pacc1;
        *(f32x8*)(zo + row0 * 272 + q * 8) = z0;
        *(f32x8*)(zo + (row0 + 1) * 272 + q * 8) = z1;
      }
      // this block's 64x64 Gram square (plain layout) + targets
      {
        const int row = tid >> 4, c4 = tid & 15;
        *(float4*)(Gb + row * 64 + c4 * 4) =
            *(const float4*)(G + (bs + row) * 1024 + bs + c4 * 4);
      }
      ((float4*)Tb)[tid] = ((const float4*)(Tg + bs * 64))[tid];
      __syncthreads();
    }

    // ---- 64 sequential steps
    for (int l = 0; l < 64; l++) {
      const int t = bs + l;
      // A: z1u = zo[l] (z1p) + in-block history; a1 = sigmoid(s1*z1u + b1)
      {
        const int j = tid >> 2, half = tid & 3;
        float a = 0.f;
        for (int lp = half; lp < l; lp += 4)
          a += ch[lp] * Gb[l * 64 + lp] * zo[lp * 272 + j];
        a += __shfl_xor(a, 1);
        a += __shfl_xor(a, 2);
        if (half == 0) {
          const float z1u = zo[l * 272 + j] + a;
          z1v[j] = z1u;
          const float z = s1 * z1u + b1v[j];
          a1v[j] = 1.f / (1.f + expf(-z));
        }
      }
      __syncthreads();
      // B1: z2 partials = a1 @ W2tile (vector FMA, f32x8 store)
      {
        f32x8 acc = {0.f, 0.f, 0.f, 0.f, 0.f, 0.f, 0.f, 0.f};
#define B1_ROW(i) acc += a1v[r * 8 + i] * W2_##i;
        ROWS8(B1_ROW)
        *(f32x8*)&scr[r * 264 + q * 8] = acc;
      }
      __syncthreads();
      // B2
      if (tid < 256) {
        float s = 0.f;
#pragma unroll
        for (int rr = 0; rr < 32; rr++) s += scr[rr * 264 + tid];
        z2v[tid] = s;
        a2v[tid] = 1.f / (1.f + expf(-(s + b2v[tid])));
      }
      __syncthreads();
      // C1: z3 partials = a2 @ W3tile
      {
        float c0a = 0.f, c1a = 0.f;
#define C1_ROW(i)                                                             \
        { const float a2x = a2v[r * 8 + i];                                   \
          c0a += a2x * W3x_##i; c1a += a2x * W3y_##i; }
        ROWS8(C1_ROW)
        scr[(q * 2 + 0) * 33 + r] = c0a;
        scr[(q * 2 + 1) * 33 + r] = c1a;
      }
      __syncthreads();
      // C2: z3, a3, softmax(-a3), d3, b3'
      if (tid < 64) {
        float s = 0.f;
#pragma unroll
        for (int rr = 0; rr < 32; rr++) s += scr[tid * 33 + rr];
        z3v[tid] = s;
        const float a3 = 1.f / (1.f + expf(-(s + b3v[tid])));
        const float e = expf(-a3);
        float tot = e;
#pragma unroll
        for (int off = 32; off > 0; off >>= 1) tot += __shfl_xor(tot, off);
        const float outv = e / tot;
        const float d3 = (Tb[l * 64 + tid] - outv) * a3 * (1.f - a3);
        d3v[tid] = d3;
        b3p[tid] = b3v[tid] - LRC * d3;
      }
      __syncthreads();
      // E1: o2 partials = W3tile @ d3
      {
        const float d0 = d3v[q * 2 + 0], d1 = d3v[q * 2 + 1];
#define E1_ROW(i) scr[(r * 8 + i) * 33 + q] = W3x_##i * d0 + W3y_##i * d1;
        ROWS8(E1_ROW)
      }
      __syncthreads();
      // E2
      if (tid < 256) {
        float s = 0.f;
#pragma unroll
        for (int qq = 0; qq < 32; qq++) s += scr[tid * 33 + qq];
        const float a2x = a2v[tid];
        const float o2 = s * a2x * (1.f - a2x);
        o2v[tid] = o2;
        b2p[tid] = b2v[tid] - LRC * o2;
      }
      __syncthreads();
      // F1: o1 partials = W2tile @ o2 (vector mul + horizontal sum)
      {
        const f32x8 ov8 = *(const f32x8*)&o2v[q * 8];
#define F1_ROW(i)                                                             \
        { f32x8 tmp = W2_##i * ov8; scr[(r * 8 + i) * 33 + q] = hsum8(tmp); }
        ROWS8(F1_ROW)
      }
      __syncthreads();
      // F2
      if (tid < 256) {
        float s = 0.f;
#pragma unroll
        for (int qq = 0; qq < 32; qq++) s += scr[tid * 33 + qq];
        const float a1x = a1v[tid];
        const float o1x = s * a1x * (1.f - a1x);
        o1v[tid] = o1x;
        zo[l * 272 + tid] = o1x;          // overwrite z1p row l with o1
        o1g[t * 256 + tid] = o1x;
        b1p[tid] = b1v[tid] - LRC * o1x;
      }
      __syncthreads();
      // G: batched dots — one per wave (16 waves, 11 dots)
      {
        const int w = tid >> 6, lane = tid & 63;
        float v = 0.f;
        if (w == 0)      { for (int i = lane; i < 256; i += 64) v += z1v[i] * o1v[i]; }
        else if (w == 1) { for (int i = lane; i < 256; i += 64) v += o1v[i] * o1v[i]; }
        else if (w == 2) { for (int i = lane; i < 256; i += 64) v += z2v[i] * o2v[i]; }
        else if (w == 3) { for (int i = lane; i < 256; i += 64) v += a1v[i] * a1v[i]; }
        else if (w == 4) { for (int i = lane; i < 256; i += 64) v += o2v[i] * o2v[i]; }
        else if (w == 5) { v = z3v[lane] * d3v[lane]; }
        else if (w == 6) { for (int i = lane; i < 256; i += 64) v += a2v[i] * a2v[i]; }
        else if (w == 7) { v = d3v[lane] * d3v[lane]; }
        else if (w == 8) { for (int i = lane; i < 256; i += 64) v += b1p[i] * b1p[i]; }
        else if (w == 9) { for (int i = lane; i < 256; i += 64) v += b2p[i] * b2p[i]; }
        else if (w == 10){ v = b3p[lane] * b3p[lane]; }
#pragma unroll
        for (int off = 32; off > 0; off >>= 1) v += __shfl_xor(v, off);
        if (lane == 0 && w < 11) dts[w] = v;
      }
      __syncthreads();
      // H: recurrences replicated on all threads (identical fp ops), then
      //    rank-1 update + renormalize W2/W3 in registers; bias renorm.
      {
        const float c1 = -LRC / s1;
        const double gtt = (double)Gb[l * 64 + l];
        const double n1 = n1d + 2.0 * (double)c1 * (double)dts[0] +
                          (double)c1 * (double)c1 * gtt * (double)dts[1];
        n1d = n1;
        const double w1n = (double)s1 * sqrt(n1);
        s1 = (float)((double)s1 / fmax(w1n, (double)EPSV));
        if (tid == 0) { ch[l] = c1; cg[t] = c1; }
        const float n2p = n2 - 2.f * LRC * dts[2] + LRC * LRC * dts[3] * dts[4];
        const float r2s = 1.f / fmaxf(sqrtf(n2p), EPSV);
        n2 = n2p * r2s * r2s;
        const float n3p = n3 - 2.f * LRC * dts[5] + LRC * LRC * dts[6] * dts[7];
        const float r3s = 1.f / fmaxf(sqrtf(n3p), EPSV);
        n3 = n3p * r3s * r3s;
        const float rb1 = 1.f / fmaxf(sqrtf(dts[8]), EPSV);
        const float rb2 = 1.f / fmaxf(sqrtf(dts[9]), EPSV);
        const float rb3 = 1.f / fmaxf(sqrtf(dts[10]), EPSV);

        const f32x8 ovs = (-LRC * r2s) * (*(const f32x8*)&o2v[q * 8]);
        const float d0s = -LRC * r3s * d3v[q * 2 + 0];
        const float d1s = -LRC * r3s * d3v[q * 2 + 1];
#define H_ROW(i)                                                              \
        { const float a1x = a1v[r * 8 + i];                                   \
          W2_##i = W2_##i * r2s + a1x * ovs;                                  \
          const float a2x = a2v[r * 8 + i];                                   \
          W3x_##i = W3x_##i * r3s + a2x * d0s;                                \
          W3y_##i = W3y_##i * r3s + a2x * d1s; }
        ROWS8(H_ROW)
        if (tid < 256) {
          b1v[tid] = b1p[tid] * rb1;
          b2v[tid] = b2p[tid] * rb2;
        }
        if (tid < 64) b3v[tid] = b3p[tid] * rb3;
      }
      __syncthreads();
    }
  }

  if (tid == 0) sclg[0] = s1;
#define OUT_ROW(i)                                                            \
  { const int row = r * 8 + i;                                                \
    *(f32x8*)(outW2 + row * 256 + q * 8) = W2_##i;                            \
    outW3[row * 64 + q * 2] = W3x_##i;                                        \
    outW3[row * 64 + q * 2 + 1] = W3y_##i; }
  ROWS8(OUT_ROW)
}

// ---------------------------------------------------------------- launch ----
extern "C" void kernel_launch(void* const* d_in, const int* in_sizes, int n_in,
                              void* d_out, int out_size, void* d_ws,
                              size_t ws_size, hipStream_t stream) {
  (void)in_sizes; (void)n_in; (void)out_size; (void)ws_size;
  const float* X   = (const float*)d_in[0];
  const float* Tg  = (const float*)d_in[1];
  const float* W1g = (const float*)d_in[2];
  const float* b1g = (const float*)d_in[3];
  const float* W2g = (const float*)d_in[4];
  const float* b2g = (const float*)d_in[5];
  const float* W3g = (const float*)d_in[6];
  const float* b3g = (const float*)d_in[7];
  float* out = (float*)d_out;
  float* ws  = (float*)d_ws;

  float* G    = ws;
  float* Z10  = G + 1048576;
  float* o1g  = Z10 + 262144;
  float* cg   = o1g + 262144;
  float* sclg = cg + 1024;

  (void)hipFuncSetAttribute((const void*)k2_seq,
                            hipFuncAttributeMaxDynamicSharedMemorySize,
                            SMEM_BYTES);

  k_gram<<<dim3(16, 16), 256, 0, stream>>>(X, G);
  k_z10<<<dim3(4, 16), 256, 0, stream>>>(X, W1g, Z10);
  k2_seq<<<dim3(1), dim3(1024), SMEM_BYTES, stream>>>(
      Tg, W1g, b1g, W2g, b2g, W3g, b3g, G, Z10, o1g, cg, sclg,
      out + 262144, out + 327680);
  k_w1out<<<dim3(4, 16), 256, 0, stream>>>(X, o1g, cg, W1g, sclg, out);
}

// Round 6
// 12742.843 us; speedup vs baseline: 1.5939x; 1.2651x over previous
//
#include <hip/hip_runtime.h>
#include <math.h>

// Backprop_29188597744223 — 1024-step sequential MLP training scan.
//
//   k_gram : G = X·Xᵀ (lower triangle + diag tiles), grid-parallel
//   k_z10  : Z10 = X·W1_init, grid-parallel
//   k2_seq : ONE workgroup, 512 threads (8 waves), __launch_bounds__(512,1)
//            -> 1 block/CU -> 2 waves/EU -> 256-VGPR budget. Thread (p,q)
//            owns a 16x8 tile of W2 as 16 named f32x8 SSA values and a
//            16x2 tile of W3 (32 scalars) — 160 persistent VGPRs, no spill.
//            W1 lazy (Gram trick; ||U1||² in double, replicated per thread),
//            W2/W3 renormalized in place each step.
//   k_w1out: W1_final = s1_f·(W1_init + Xᵀ·diag(c)·O1), grid-parallel

#define LRC  0.01f
#define EPSV 1e-8f

typedef float f32x8 __attribute__((ext_vector_type(8)));

#define SMEM_FLOATS 36976
#define SMEM_BYTES  (SMEM_FLOATS * 4)

#define ROWS16(OP)                                                            \
  OP(0) OP(1) OP(2) OP(3) OP(4) OP(5) OP(6) OP(7)                             \
  OP(8) OP(9) OP(10) OP(11) OP(12) OP(13) OP(14) OP(15)

__device__ __forceinline__ float hsum8(f32x8 v) {
  return ((v.s0 + v.s1) + (v.s2 + v.s3)) + ((v.s4 + v.s5) + (v.s6 + v.s7));
}

#define FMA16(c, a, b)                                                        \
  c[0][0] += a.x * b.x; c[0][1] += a.x * b.y; c[0][2] += a.x * b.z; c[0][3] += a.x * b.w; \
  c[1][0] += a.y * b.x; c[1][1] += a.y * b.y; c[1][2] += a.y * b.z; c[1][3] += a.y * b.w; \
  c[2][0] += a.z * b.x; c[2][1] += a.z * b.y; c[2][2] += a.z * b.z; c[2][3] += a.z * b.w; \
  c[3][0] += a.w * b.x; c[3][1] += a.w * b.y; c[3][2] += a.w * b.z; c[3][3] += a.w * b.w;

// ---------------------------------------------------------------- k_gram ----
__global__ __launch_bounds__(256) void k_gram(const float* __restrict__ X,
                                              float* __restrict__ G) {
  const int bi = blockIdx.y, bj = blockIdx.x;
  if (bj > bi) return;
  __shared__ float Xa[32][68];
  __shared__ float Xb[32][68];
  const int tid = threadIdx.x;
  const int tx = tid & 15, ty = tid >> 4;
  float c[4][4] = {};
  for (int k0 = 0; k0 < 1024; k0 += 32) {
    __syncthreads();
    {
      const int row = tid >> 2, kk = (tid & 3) * 8;
      const float* pa = X + (bi * 64 + row) * 1024 + k0 + kk;
      const float4 a0 = *(const float4*)pa;
      const float4 a1 = *(const float4*)(pa + 4);
      Xa[kk + 0][row] = a0.x; Xa[kk + 1][row] = a0.y;
      Xa[kk + 2][row] = a0.z; Xa[kk + 3][row] = a0.w;
      Xa[kk + 4][row] = a1.x; Xa[kk + 5][row] = a1.y;
      Xa[kk + 6][row] = a1.z; Xa[kk + 7][row] = a1.w;
      const float* pb = X + (bj * 64 + row) * 1024 + k0 + kk;
      const float4 b0 = *(const float4*)pb;
      const float4 b1 = *(const float4*)(pb + 4);
      Xb[kk + 0][row] = b0.x; Xb[kk + 1][row] = b0.y;
      Xb[kk + 2][row] = b0.z; Xb[kk + 3][row] = b0.w;
      Xb[kk + 4][row] = b1.x; Xb[kk + 5][row] = b1.y;
      Xb[kk + 6][row] = b1.z; Xb[kk + 7][row] = b1.w;
    }
    __syncthreads();
#pragma unroll
    for (int kk = 0; kk < 32; kk++) {
      const float4 a = *(const float4*)&Xa[kk][ty * 4];
      const float4 b = *(const float4*)&Xb[kk][tx * 4];
      FMA16(c, a, b)
    }
  }
#pragma unroll
  for (int ii = 0; ii < 4; ii++) {
    *(float4*)(G + (bi * 64 + ty * 4 + ii) * 1024 + bj * 64 + tx * 4) =
        make_float4(c[ii][0], c[ii][1], c[ii][2], c[ii][3]);
  }
}

// ----------------------------------------------------------------- k_z10 ----
__global__ __launch_bounds__(256) void k_z10(const float* __restrict__ X,
                                             const float* __restrict__ W1g,
                                             float* __restrict__ Z10) {
  const int bi = blockIdx.y, bj = blockIdx.x;
  __shared__ float At[32][68];
  __shared__ float Bt[32][68];
  const int tid = threadIdx.x;
  const int tx = tid & 15, ty = tid >> 4;
  float c[4][4] = {};
  for (int k0 = 0; k0 < 1024; k0 += 32) {
    __syncthreads();
    {
      const int row = tid >> 2, kk = (tid & 3) * 8;
      const float* pa = X + (bi * 64 + row) * 1024 + k0 + kk;
      const float4 a0 = *(const float4*)pa;
      const float4 a1 = *(const float4*)(pa + 4);
      At[kk + 0][row] = a0.x; At[kk + 1][row] = a0.y;
      At[kk + 2][row] = a0.z; At[kk + 3][row] = a0.w;
      At[kk + 4][row] = a1.x; At[kk + 5][row] = a1.y;
      At[kk + 6][row] = a1.z; At[kk + 7][row] = a1.w;
      const int kr = tid >> 3, j8 = (tid & 7) * 8;
      const float* pb = W1g + (k0 + kr) * 256 + bj * 64 + j8;
      *(float4*)&Bt[kr][j8]     = *(const float4*)pb;
      *(float4*)&Bt[kr][j8 + 4] = *(const float4*)(pb + 4);
    }
    __syncthreads();
#pragma unroll
    for (int kk = 0; kk < 32; kk++) {
      const float4 a = *(const float4*)&At[kk][ty * 4];
      const float4 b = *(const float4*)&Bt[kk][tx * 4];
      FMA16(c, a, b)
    }
  }
#pragma unroll
  for (int ii = 0; ii < 4; ii++) {
    *(float4*)(Z10 + (bi * 64 + ty * 4 + ii) * 256 + bj * 64 + tx * 4) =
        make_float4(c[ii][0], c[ii][1], c[ii][2], c[ii][3]);
  }
}

// --------------------------------------------------------------- k_w1out ----
__global__ __launch_bounds__(256) void k_w1out(
    const float* __restrict__ X, const float* __restrict__ o1g,
    const float* __restrict__ cg, const float* __restrict__ W1g,
    const float* __restrict__ sclg, float* __restrict__ outW1) {
  const int bi = blockIdx.y, bj = blockIdx.x;
  __shared__ float At[32][68];
  __shared__ float Bt[32][68];
  const int tid = threadIdx.x;
  const int tx = tid & 15, ty = tid >> 4;
  float c[4][4] = {};
  for (int k0 = 0; k0 < 1024; k0 += 32) {
    __syncthreads();
    {
      const int kr = tid >> 3, m8 = (tid & 7) * 8;
      const float* pa = X + (k0 + kr) * 1024 + bi * 64 + m8;
      *(float4*)&At[kr][m8]     = *(const float4*)pa;
      *(float4*)&At[kr][m8 + 4] = *(const float4*)(pa + 4);
      const float cs = cg[k0 + kr];
      const float* pb = o1g + (k0 + kr) * 256 + bj * 64 + m8;
      float4 b0 = *(const float4*)pb;
      float4 b1 = *(const float4*)(pb + 4);
      b0.x *= cs; b0.y *= cs; b0.z *= cs; b0.w *= cs;
      b1.x *= cs; b1.y *= cs; b1.z *= cs; b1.w *= cs;
      *(float4*)&Bt[kr][m8]     = b0;
      *(float4*)&Bt[kr][m8 + 4] = b1;
    }
    __syncthreads();
#pragma unroll
    for (int kk = 0; kk < 32; kk++) {
      const float4 a = *(const float4*)&At[kk][ty * 4];
      const float4 b = *(const float4*)&Bt[kk][tx * 4];
      FMA16(c, a, b)
    }
  }
  const float s1f = sclg[0];
#pragma unroll
  for (int ii = 0; ii < 4; ii++) {
    const int row = bi * 64 + ty * 4 + ii;
    const float4 w = *(const float4*)(W1g + row * 256 + bj * 64 + tx * 4);
    *(float4*)(outW1 + row * 256 + bj * 64 + tx * 4) =
        make_float4(s1f * (w.x + c[ii][0]), s1f * (w.y + c[ii][1]),
                    s1f * (w.z + c[ii][2]), s1f * (w.w + c[ii][3]));
  }
}

// ---------------------------------------------------------------- k2_seq ----
__device__ __forceinline__ float block_reduce8(float v, float* tmp, int tid) {
#pragma unroll
  for (int off = 32; off > 0; off >>= 1) v += __shfl_xor(v, off);
  __syncthreads();
  if ((tid & 63) == 0) tmp[tid >> 6] = v;
  __syncthreads();
  float s = 0.f;
#pragma unroll
  for (int w = 0; w < 8; w++) s += tmp[w];
  __syncthreads();
  return s;
}

__global__ __launch_bounds__(512, 1) void k2_seq(
    const float* __restrict__ Tg, const float* __restrict__ W1g,
    const float* __restrict__ b1g, const float* __restrict__ W2g,
    const float* __restrict__ b2g, const float* __restrict__ W3g,
    const float* __restrict__ b3g, const float* __restrict__ G,
    const float* __restrict__ Z10, float* __restrict__ o1g,
    float* __restrict__ cg, float* __restrict__ sclg,
    float* __restrict__ outW2, float* __restrict__ outW3) {
  extern __shared__ float sm[];
  float* const zo  = sm;           // [64][272]: z1p row l until step l, then o1
  float* const Gb  = sm + 17408;   // [64][64] plain / [64][33] prefix staging
  float* const scr = sm + 21504;   // 8448 floats: partials / o1 staging
  float* const Tb  = sm + 29952;   // [64][64] targets for this block
  float* const a1v = sm + 34048;
  float* const z1v = sm + 34304;
  float* const z2v = sm + 34560;
  float* const a2v = sm + 34816;
  float* const o2v = sm + 35072;
  float* const o1v = sm + 35328;
  float* const b1v = sm + 35584;
  float* const b2v = sm + 35840;
  float* const b1p = sm + 36096;
  float* const b2p = sm + 36352;
  float* const z3v = sm + 36608;   // 64
  float* const d3v = sm + 36672;   // 64
  float* const b3v = sm + 36736;   // 64
  float* const b3p = sm + 36800;   // 64
  float* const ch  = sm + 36864;   // 64
  float* const dts = sm + 36928;   // 16
  float* const cpre = sm + 36944;  // 32

  const int tid = threadIdx.x;
  const int p = tid >> 5;  // 0..15 : 16-row group
  const int q = tid & 31;  // 0..31 : 8-col group (W2) / 2-col group (W3)

  // ---- persistent per-thread state as named SSA values (no arrays!) ----
  f32x8 W2_0, W2_1, W2_2, W2_3, W2_4, W2_5, W2_6, W2_7,
        W2_8, W2_9, W2_10, W2_11, W2_12, W2_13, W2_14, W2_15;
  float W3x_0, W3x_1, W3x_2, W3x_3, W3x_4, W3x_5, W3x_6, W3x_7,
        W3x_8, W3x_9, W3x_10, W3x_11, W3x_12, W3x_13, W3x_14, W3x_15;
  float W3y_0, W3y_1, W3y_2, W3y_3, W3y_4, W3y_5, W3y_6, W3y_7,
        W3y_8, W3y_9, W3y_10, W3y_11, W3y_12, W3y_13, W3y_14, W3y_15;

#define INIT_ROW(i)                                                           \
  { const int row = p * 16 + i;                                               \
    W2_##i  = *(const f32x8*)(W2g + row * 256 + q * 8);                       \
    W3x_##i = W3g[row * 64 + q * 2];                                          \
    W3y_##i = W3g[row * 64 + q * 2 + 1]; }
  ROWS16(INIT_ROW)

  if (tid < 256) { b1v[tid] = b1g[tid]; b2v[tid] = b2g[tid]; }
  if (tid < 64) b3v[tid] = b3g[tid];

  // Initial squared norms (broadcast to all threads).
  float acc1 = 0.f;
  for (int i = tid; i < 65536; i += 512) {
    const float4 v = ((const float4*)W1g)[i];
    acc1 += v.x * v.x + v.y * v.y + v.z * v.z + v.w * v.w;
  }
  const float n1init = block_reduce8(acc1, scr, tid);
  float acc2 = 0.f;
#define N2_ROW(i) { f32x8 t = W2_##i * W2_##i; acc2 += hsum8(t); }
  ROWS16(N2_ROW)
  const float n2init = block_reduce8(acc2, scr, tid);
  float acc3 = 0.f;
#define N3_ROW(i) acc3 += W3x_##i * W3x_##i + W3y_##i * W3y_##i;
  ROWS16(N3_ROW)
  const float n3init = block_reduce8(acc3, scr, tid);

  // Per-thread replicated recurrence state (identical on all threads).
  float s1 = 1.f;
  double n1d = (double)n1init;
  float n2 = n2init, n3 = n3init;
  __syncthreads();

  for (int b = 0; b < 16; b++) {
    const int bs = b * 64;
    // ---- prefix: zo[row][j] = Z10[bs+row][j] + sum_{s<bs} cg[s]G[bs+row][s]o1[s][j]
    {
      f32x8 pacc0 = {0.f, 0.f, 0.f, 0.f, 0.f, 0.f, 0.f, 0.f};
      f32x8 pacc1 = pacc0, pacc2 = pacc0, pacc3 = pacc0;
      for (int c0 = 0; c0 < bs; c0 += 32) {
        __syncthreads();
        if (tid < 32) cpre[tid] = cg[c0 + tid];
        {
          const int row = tid >> 3, k4 = (tid & 7) * 4;
          const float4 gv = *(const float4*)(G + (bs + row) * 1024 + c0 + k4);
          Gb[row * 33 + k4 + 0] = gv.x; Gb[row * 33 + k4 + 1] = gv.y;
          Gb[row * 33 + k4 + 2] = gv.z; Gb[row * 33 + k4 + 3] = gv.w;
        }
#pragma unroll
        for (int u = 0; u < 4; u++) {
          const int fi = tid + u * 512;
          ((float4*)scr)[fi] = ((const float4*)(o1g + c0 * 256))[fi];
        }
        __syncthreads();
#pragma unroll 2
        for (int ss = 0; ss < 32; ss++) {
          const float cs = cpre[ss];
          const f32x8 o8 = *(const f32x8*)(scr + ss * 256 + q * 8);
          pacc0 += (Gb[(p * 4 + 0) * 33 + ss] * cs) * o8;
          pacc1 += (Gb[(p * 4 + 1) * 33 + ss] * cs) * o8;
          pacc2 += (Gb[(p * 4 + 2) * 33 + ss] * cs) * o8;
          pacc3 += (Gb[(p * 4 + 3) * 33 + ss] * cs) * o8;
        }
      }
      __syncthreads();
#define ZSTORE(rr)                                                            \
      { const int row = p * 4 + rr;                                           \
        *(f32x8*)(zo + row * 272 + q * 8) =                                   \
            *(const f32x8*)(Z10 + (bs + row) * 256 + q * 8) + pacc##rr; }
      ZSTORE(0) ZSTORE(1) ZSTORE(2) ZSTORE(3)
      // this block's 64x64 Gram square (plain layout) + targets
#pragma unroll
      for (int u = 0; u < 2; u++) {
        const int fi = tid + u * 512;
        const int row = fi >> 4, c4 = fi & 15;
        *(float4*)(Gb + row * 64 + c4 * 4) =
            *(const float4*)(G + (bs + row) * 1024 + bs + c4 * 4);
      }
      ((float4*)Tb)[tid]       = ((const float4*)(Tg + bs * 64))[tid];
      ((float4*)Tb)[tid + 512] = ((const float4*)(Tg + bs * 64))[tid + 512];
      __syncthreads();
    }

    // ---- 64 sequential steps
    for (int l = 0; l < 64; l++) {
      const int t = bs + l;
      // A: z1u = zo[l] (z1p) + in-block history; a1 = sigmoid(s1*z1u + b1)
      {
        const int j = tid >> 1, half = tid & 1;
        float a = 0.f;
        for (int lp = half; lp < l; lp += 2)
          a += ch[lp] * Gb[l * 64 + lp] * zo[lp * 272 + j];
        a += __shfl_xor(a, 1);
        if (half == 0) {
          const float z1u = zo[l * 272 + j] + a;
          z1v[j] = z1u;
          const float z = s1 * z1u + b1v[j];
          a1v[j] = 1.f / (1.f + expf(-z));
        }
      }
      __syncthreads();
      // B1: z2 partials = a1 @ W2tile (vector FMA, f32x8 store)
      {
        f32x8 acc = {0.f, 0.f, 0.f, 0.f, 0.f, 0.f, 0.f, 0.f};
#define B1_ROW(i) acc += a1v[p * 16 + i] * W2_##i;
        ROWS16(B1_ROW)
        *(f32x8*)&scr[p * 264 + q * 8] = acc;
      }
      __syncthreads();
      // B2
      if (tid < 256) {
        float s = 0.f;
#pragma unroll
        for (int pp = 0; pp < 16; pp++) s += scr[pp * 264 + tid];
        z2v[tid] = s;
        a2v[tid] = 1.f / (1.f + expf(-(s + b2v[tid])));
      }
      __syncthreads();
      // C1: z3 partials = a2 @ W3tile
      {
        float c0a = 0.f, c1a = 0.f;
#define C1_ROW(i)                                                             \
        { const float a2x = a2v[p * 16 + i];                                  \
          c0a += a2x * W3x_##i; c1a += a2x * W3y_##i; }
        ROWS16(C1_ROW)
        scr[(q * 2 + 0) * 17 + p] = c0a;
        scr[(q * 2 + 1) * 17 + p] = c1a;
      }
      __syncthreads();
      // C2: z3, a3, softmax(-a3), d3, b3'
      if (tid < 64) {
        float s = 0.f;
#pragma unroll
        for (int pp = 0; pp < 16; pp++) s += scr[tid * 17 + pp];
        z3v[tid] = s;
        const float a3 = 1.f / (1.f + expf(-(s + b3v[tid])));
        const float e = expf(-a3);
        float tot = e;
#pragma unroll
        for (int off = 32; off > 0; off >>= 1) tot += __shfl_xor(tot, off);
        const float outv = e / tot;
        const float d3 = (Tb[l * 64 + tid] - outv) * a3 * (1.f - a3);
        d3v[tid] = d3;
        b3p[tid] = b3v[tid] - LRC * d3;
      }
      __syncthreads();
      // E1: o2 partials = W3tile @ d3
      {
        const float d0 = d3v[q * 2 + 0], d1 = d3v[q * 2 + 1];
#define E1_ROW(i) scr[(p * 16 + i) * 33 + q] = W3x_##i * d0 + W3y_##i * d1;
        ROWS16(E1_ROW)
      }
      __syncthreads();
      // E2
      if (tid < 256) {
        float s = 0.f;
#pragma unroll
        for (int qq = 0; qq < 32; qq++) s += scr[tid * 33 + qq];
        const float a2x = a2v[tid];
        const float o2 = s * a2x * (1.f - a2x);
        o2v[tid] = o2;
        b2p[tid] = b2v[tid] - LRC * o2;
      }
      __syncthreads();
      // F1: o1 partials = W2tile @ o2 (vector mul + horizontal sum)
      {
        const f32x8 ov8 = *(const f32x8*)&o2v[q * 8];
#define F1_ROW(i)                                                             \
        { f32x8 tmp = W2_##i * ov8; scr[(p * 16 + i) * 33 + q] = hsum8(tmp); }
        ROWS16(F1_ROW)
      }
      __syncthreads();
      // F2
      if (tid < 256) {
        float s = 0.f;
#pragma unroll
        for (int qq = 0; qq < 32; qq++) s += scr[tid * 33 + qq];
        const float a1x = a1v[tid];
        const float o1x = s * a1x * (1.f - a1x);
        o1v[tid] = o1x;
        zo[l * 272 + tid] = o1x;          // overwrite z1p row l with o1
        o1g[t * 256 + tid] = o1x;
        b1p[tid] = b1v[tid] - LRC * o1x;
      }
      __syncthreads();
      // G: batched dots — 11 dots over 8 waves, two rounds
      {
        const int w = tid >> 6, lane = tid & 63;
        float v = 0.f;
        if (w == 0)      { for (int i = lane; i < 256; i += 64) v += z1v[i] * o1v[i]; }
        else if (w == 1) { for (int i = lane; i < 256; i += 64) v += o1v[i] * o1v[i]; }
        else if (w == 2) { for (int i = lane; i < 256; i += 64) v += z2v[i] * o2v[i]; }
        else if (w == 3) { for (int i = lane; i < 256; i += 64) v += a1v[i] * a1v[i]; }
        else if (w == 4) { for (int i = lane; i < 256; i += 64) v += o2v[i] * o2v[i]; }
        else if (w == 5) { v = z3v[lane] * d3v[lane]; }
        else if (w == 6) { for (int i = lane; i < 256; i += 64) v += a2v[i] * a2v[i]; }
        else             { v = d3v[lane] * d3v[lane]; }
#pragma unroll
        for (int off = 32; off > 0; off >>= 1) v += __shfl_xor(v, off);
        if (lane == 0) dts[w] = v;
        float v2 = 0.f;
        if (w == 0)      { for (int i = lane; i < 256; i += 64) v2 += b1p[i] * b1p[i]; }
        else if (w == 1) { for (int i = lane; i < 256; i += 64) v2 += b2p[i] * b2p[i]; }
        else if (w == 2) { v2 = b3p[lane] * b3p[lane]; }
#pragma unroll
        for (int off = 32; off > 0; off >>= 1) v2 += __shfl_xor(v2, off);
        if (lane == 0 && w < 3) dts[8 + w] = v2;
      }
      __syncthreads();
      // H: recurrences replicated on all threads (identical fp ops), then
      //    rank-1 update + renormalize W2/W3 in registers; bias renorm.
      {
        const float c1 = -LRC / s1;
        const double gtt = (double)Gb[l * 64 + l];
        const double n1 = n1d + 2.0 * (double)c1 * (double)dts[0] +
                          (double)c1 * (double)c1 * gtt * (double)dts[1];
        n1d = n1;
        const double w1n = (double)s1 * sqrt(n1);
        s1 = (float)((double)s1 / fmax(w1n, (double)EPSV));
        if (tid == 0) { ch[l] = c1; cg[t] = c1; }
        const float n2p = n2 - 2.f * LRC * dts[2] + LRC * LRC * dts[3] * dts[4];
        const float r2s = 1.f / fmaxf(sqrtf(n2p), EPSV);
        n2 = n2p * r2s * r2s;
        const float n3p = n3 - 2.f * LRC * dts[5] + LRC * LRC * dts[6] * dts[7];
        const float r3s = 1.f / fmaxf(sqrtf(n3p), EPSV);
        n3 = n3p * r3s * r3s;
        const float rb1 = 1.f / fmaxf(sqrtf(dts[8]), EPSV);
        const float rb2 = 1.f / fmaxf(sqrtf(dts[9]), EPSV);
        const float rb3 = 1.f / fmaxf(sqrtf(dts[10]), EPSV);

        const f32x8 ovs = (-LRC * r2s) * (*(const f32x8*)&o2v[q * 8]);
        const float d0s = -LRC * r3s * d3v[q * 2 + 0];
        const float d1s = -LRC * r3s * d3v[q * 2 + 1];
#define H_ROW(i)                                                              \
        { const float a1x = a1v[p * 16 + i];                                  \
          W2_##i = W2_##i * r2s + a1x * ovs;                                  \
          const float a2x = a2v[p * 16 + i];                                  \
          W3x_##i = W3x_##i * r3s + a2x * d0s;                                \
          W3y_##i = W3y_##i * r3s + a2x * d1s; }
        ROWS16(H_ROW)
        if (tid < 256) {
          b1v[tid] = b1p[tid] * rb1;
          b2v[tid] = b2p[tid] * rb2;
        }
        if (tid < 64) b3v[tid] = b3p[tid] * rb3;
      }
      __syncthreads();
    }
  }

  if (tid == 0) sclg[0] = s1;
#define OUT_ROW(i)                                                            \
  { const int row = p * 16 + i;                                               \
    *(f32x8*)(outW2 + row * 256 + q * 8) = W2_##i;                            \
    outW3[row * 64 + q * 2] = W3x_##i;                                        \
    outW3[row * 64 + q * 2 + 1] = W3y_##i; }
  ROWS16(OUT_ROW)
}

// ---------------------------------------------------------------- launch ----
extern "C" void kernel_launch(void* const* d_in, const int* in_sizes, int n_in,
                              void* d_out, int out_size, void* d_ws,
                              size_t ws_size, hipStream_t stream) {
  (void)in_sizes; (void)n_in; (void)out_size; (void)ws_size;
  const float* X   = (const float*)d_in[0];
  const float* Tg  = (const float*)d_in[1];
  const float* W1g = (const float*)d_in[2];
  const float* b1g = (const float*)d_in[3];
  const float* W2g = (const float*)d_in[4];
  const float* b2g = (const float*)d_in[5];
  const float* W3g = (const float*)d_in[6];
  const float* b3g = (const float*)d_in[7];
  float* out = (float*)d_out;
  float* ws  = (float*)d_ws;

  float* G    = ws;
  float* Z10  = G + 1048576;
  float* o1g  = Z10 + 262144;
  float* cg   = o1g + 262144;
  float* sclg = cg + 1024;

  (void)hipFuncSetAttribute((const void*)k2_seq,
                            hipFuncAttributeMaxDynamicSharedMemorySize,
                            SMEM_BYTES);

  k_gram<<<dim3(16, 16), 256, 0, stream>>>(X, G);
  k_z10<<<dim3(4, 16), 256, 0, stream>>>(X, W1g, Z10);
  k2_seq<<<dim3(1), dim3(512), SMEM_BYTES, stream>>>(
      Tg, W1g, b1g, W2g, b2g, W3g, b3g, G, Z10, o1g, cg, sclg,
      out + 262144, out + 327680);
  k_w1out<<<dim3(4, 16), 256, 0, stream>>>(X, o1g, cg, W1g, sclg, out);
}